// Round 1
// baseline (600.415 us; speedup 1.0000x reference)
//
#include <hip/hip_runtime.h>

#define BATCH 2
#define CIN   64
#define CIC   67      // 64 + 3 coord channels
#define COFF  108
#define COUT  64
#define DD    8
#define HHH   32
#define WWW   32
#define HWs   1024    // 32*32
#define DHW   8192    // 8*32*32
#define KTAP  27
#define CK    1728    // 64*27

// ---------------- kernel 0: weight transposes into workspace ----------------
// wT_off[ci][tap][co]  from w_off[co][ci][tap]   (108,67,27)
// wT_dcn[ck][o]        from w_dcn[o][ck]         (64, 1728)
__global__ void k_transpose(const float* __restrict__ w_off,
                            const float* __restrict__ w_dcn,
                            float* __restrict__ wT_off,
                            float* __restrict__ wT_dcn)
{
    int stride = gridDim.x * blockDim.x;
    int t0 = blockIdx.x * blockDim.x + threadIdx.x;
    for (int i = t0; i < CIC * KTAP * COFF; i += stride) {
        int co = i % COFF; int r = i / COFF; int tap = r % KTAP; int ci = r / KTAP;
        wT_off[i] = w_off[(co * CIC + ci) * KTAP + tap];
    }
    for (int i = t0; i < CK * COUT; i += stride) {
        int o = i & 63; int ck = i >> 6;
        wT_dcn[i] = w_dcn[o * CK + ck];
    }
}

// ---------------- kernel 1: offset conv (pred = conv3d(add_coords(x))) -------
// one block per (b,d,h); LDS-staged input slab; 4x4 register tile per thread
__global__ __launch_bounds__(256) void k_offset_conv(
    const float* __restrict__ x,
    const float* __restrict__ wT,      // [ci][tap][108]
    const float* __restrict__ b_off,
    float* __restrict__ pred)          // [b][108][8192]
{
    __shared__ float xs[CIC * 9 * 36];   // [ci][dz][dy][36], rows padded to 36
    const int bid = blockIdx.x;
    const int b = bid >> 8;
    const int d = (bid >> 5) & 7;
    const int h = bid & 31;
    const int tid = threadIdx.x;

    // stage x + coords with zero padding (w range -1..32 -> 34 entries)
    for (int idx = tid; idx < CIC * 9 * 34; idx += 256) {
        int w34 = idx % 34;
        int r = idx / 34;
        int dy = r % 3; r /= 3;
        int dz = r % 3;
        int ci = r / 3;
        int dd = d + dz - 1, hh = h + dy - 1, ww = w34 - 1;
        float v = 0.f;
        if (dd >= 0 && dd < DD && hh >= 0 && hh < HHH && ww >= 0 && ww < WWW) {
            if (ci < CIN)      v = x[(((size_t)(b * CIN + ci) * DD + dd) * HHH + hh) * WWW + ww];
            else if (ci == 64) v = -1.f + (2.f / 7.f)  * (float)dd;
            else if (ci == 65) v = -1.f + (2.f / 31.f) * (float)hh;
            else               v = -1.f + (2.f / 31.f) * (float)ww;
        }
        xs[((ci * 3 + dz) * 3 + dy) * 36 + w34] = v;
    }
    __syncthreads();

    if (tid >= 216) return;               // 27 co-groups x 8 w-groups
    const int co0 = (tid / 8) * 4;
    const int w0  = (tid % 8) * 4;

    float acc[4][4] = {};

    for (int ci = 0; ci < CIC; ++ci) {
        const float* __restrict__ wrow = wT + (size_t)(ci * KTAP) * COFF + co0;
        const float* __restrict__ xrow = xs + ci * 9 * 36 + w0;
        #pragma unroll
        for (int dz = 0; dz < 3; ++dz) {
            #pragma unroll
            for (int dy = 0; dy < 3; ++dy) {
                const float* xr = xrow + (dz * 3 + dy) * 36;   // 16B aligned
                float4 xa = *(const float4*)xr;
                float2 xb = *(const float2*)(xr + 4);
                float xv[6] = {xa.x, xa.y, xa.z, xa.w, xb.x, xb.y};
                #pragma unroll
                for (int kw = 0; kw < 3; ++kw) {
                    float4 wv = *(const float4*)(wrow + ((dz * 3 + dy) * 3 + kw) * COFF);
                    #pragma unroll
                    for (int i = 0; i < 4; ++i) {
                        float wvi = (i == 0) ? wv.x : (i == 1) ? wv.y : (i == 2) ? wv.z : wv.w;
                        #pragma unroll
                        for (int j = 0; j < 4; ++j)
                            acc[i][j] += wvi * xv[kw + j];
                    }
                }
            }
        }
    }

    const int sp = d * HWs + h * WWW + w0;
    #pragma unroll
    for (int i = 0; i < 4; ++i) {
        float bo = b_off[co0 + i];
        #pragma unroll
        for (int j = 0; j < 4; ++j)
            pred[((size_t)b * COFF + co0 + i) * DHW + sp + j] = acc[i][j] + bo;
    }
}

// ---------------- kernel 2: deformable sample + matvec -----------------------
// one block per (b,d,h); two 16-wide w halves
__global__ __launch_bounds__(256) void k_dcn(
    const float* __restrict__ x,
    const float* __restrict__ pred,
    const float* __restrict__ wT,     // [1728][64]
    const float* __restrict__ b_dcn,
    float* __restrict__ out)          // [b][64][8192]
{
    __shared__ float  s[CK * 16];         // [ck][p]  110592 B
    __shared__ float2 cw[27 * 16 * 9];    // [(k*16+p)][corner(8, padded to 9)] = (idx bits, wgt*alpha)
    const int bid = blockIdx.x;
    const int b = bid >> 8;
    const int d = (bid >> 5) & 7;
    const int h = bid & 31;
    const int tid = threadIdx.x;
    const float* __restrict__ xb0   = x    + (size_t)b * CIN  * DHW;
    const float* __restrict__ predb = pred + (size_t)b * COFF * DHW;

    for (int half = 0; half < 2; ++half) {
        // ---- A0: per-(k,p) corner tables (weights folded with alpha) ----
        for (int kp = tid; kp < 27 * 16; kp += 256) {
            int k = kp >> 4, p = kp & 15;
            int w = half * 16 + p;
            int sp = d * HWs + h * WWW + w;
            float offz = predb[(k * 3 + 0) * DHW + sp];
            float offy = predb[(k * 3 + 1) * DHW + sp];
            float offx = predb[(k * 3 + 2) * DHW + sp];
            float aval = predb[(81 + k) * DHW + sp];
            float alpha = 1.f / (1.f + expf(-aval));
            float kz = (float)(k / 9) - 1.f;
            float ky = (float)((k / 3) % 3) - 1.f;
            float kx = (float)(k % 3) - 1.f;
            float pz = (float)d + kz + offz;
            float py = (float)h + ky + offy;
            float px = (float)w + kx + offx;
            float fz = floorf(pz), fy = floorf(py), fx = floorf(px);
            float tz = pz - fz, ty = py - fy, tx = px - fx;
            #pragma unroll
            for (int c8 = 0; c8 < 8; ++c8) {
                int cz = (c8 >> 2) & 1, cy = (c8 >> 1) & 1, cx = c8 & 1;
                float iz = fz + cz, iy = fy + cy, ix = fx + cx;
                float wz = cz ? tz : 1.f - tz;
                float wy = cy ? ty : 1.f - ty;
                float wx = cx ? tx : 1.f - tx;
                bool valid = (iz >= 0.f) & (iz <= 7.f) & (iy >= 0.f) & (iy <= 31.f)
                           & (ix >= 0.f) & (ix <= 31.f);
                int flat = valid ? (((int)iz) * HWs + ((int)iy) * WWW + (int)ix) : 0;
                float wgt = valid ? wz * wy * wx * alpha : 0.f;
                cw[kp * 9 + c8] = make_float2(__int_as_float(flat), wgt);
            }
        }
        __syncthreads();

        // ---- A: gather-sample all channels into s[ck][p] ----
        for (int idx = tid; idx < CIN * 27 * 16; idx += 256) {
            int p = idx & 15;
            int k = (idx >> 4) % 27;
            int c = idx / 432;
            const float* __restrict__ xc = xb0 + (size_t)c * DHW;
            const float2* __restrict__ cwp = cw + (k * 16 + p) * 9;
            float acc = 0.f;
            #pragma unroll
            for (int c8 = 0; c8 < 8; ++c8) {
                float2 iw = cwp[c8];
                acc += iw.y * xc[__float_as_int(iw.x)];
            }
            s[(c * 27 + k) * 16 + p] = acc;
        }
        __syncthreads();

        // ---- B: out[o, p0..p0+3] = sum_ck wT[ck][o] * s[ck][p] ----
        {
            const int o  = tid & 63;
            const int p0 = (tid >> 6) * 4;
            float a0 = 0.f, a1 = 0.f, a2 = 0.f, a3 = 0.f;
            #pragma unroll 4
            for (int ck = 0; ck < CK; ++ck) {
                float wv = wT[ck * 64 + o];
                float4 sv = *(const float4*)&s[ck * 16 + p0];   // uniform addr -> broadcast
                a0 += wv * sv.x; a1 += wv * sv.y; a2 += wv * sv.z; a3 += wv * sv.w;
            }
            float bo = b_dcn[o];
            size_t obase = ((size_t)b * COUT + o) * DHW + d * HWs + h * WWW + half * 16 + p0;
            out[obase + 0] = a0 + bo;
            out[obase + 1] = a1 + bo;
            out[obase + 2] = a2 + bo;
            out[obase + 3] = a3 + bo;
        }
        __syncthreads();   // protect s before next half overwrites
    }
}

extern "C" void kernel_launch(void* const* d_in, const int* in_sizes, int n_in,
                              void* d_out, int out_size, void* d_ws, size_t ws_size,
                              hipStream_t stream) {
    const float* x     = (const float*)d_in[0];
    const float* w_off = (const float*)d_in[1];
    const float* b_off = (const float*)d_in[2];
    const float* w_dcn = (const float*)d_in[3];
    const float* b_dcn = (const float*)d_in[4];
    float* out = (float*)d_out;

    // workspace layout
    float* pred   = (float*)d_ws;                               // 1,769,472 f = 7,077,888 B
    float* wT_off = (float*)((char*)d_ws + 7077888);            // 195,372 f  =   781,488 B
    float* wT_dcn = (float*)((char*)d_ws + 7859376);            // 110,592 f  =   442,368 B

    k_transpose<<<256, 256, 0, stream>>>(w_off, w_dcn, wT_off, wT_dcn);
    k_offset_conv<<<BATCH * DD * HHH, 256, 0, stream>>>(x, wT_off, b_off, pred);
    k_dcn<<<BATCH * DD * HHH, 256, 0, stream>>>(x, pred, wT_dcn, b_dcn, out);
}

// Round 2
// 309.077 us; speedup vs baseline: 1.9426x; 1.9426x over previous
//
#include <hip/hip_runtime.h>

#define DD    8
#define HHH   32
#define WWW   32
#define DHW   8192
#define CIN   64
#define COFF  108
#define COUT  64

typedef __attribute__((ext_vector_type(8))) short bf16x8;
typedef __attribute__((ext_vector_type(4))) float f32x4;

__device__ inline unsigned short f2bf(float f) {
    unsigned u = __float_as_uint(f);
    u += 0x7fffu + ((u >> 16) & 1u);     // RNE
    return (unsigned short)(u >> 16);
}

// ---------------- kernel 0: pack weights into MFMA A-fragment order ---------
// pA (stage1, A=W_off, M=co pad 112, K=32/chunk pad):   i = ((ci*7+m)*64+l)*8+j
//    co = m*16 + (l&15), tap = (l>>4)*8 + j  (0 if co>=108 or tap>=27)
// pW (stage2, A=W_dcn, M=o, K=64/chunk):  i = (((k*4+w)*2+jf)*64+l)*8+jj
//    o = w*16 + (l&15), c = jf*32 + (l>>4)*8 + jj
__global__ void k_pack(const float* __restrict__ w_off,
                       const float* __restrict__ w_dcn,
                       ushort* __restrict__ pA,
                       ushort* __restrict__ pW)
{
    int t0 = blockIdx.x * blockDim.x + threadIdx.x;
    int stride = gridDim.x * blockDim.x;
    for (int i = t0; i < 67 * 7 * 64 * 8; i += stride) {
        int j = i & 7; int l = (i >> 3) & 63; int cm = i >> 9;
        int m = cm % 7; int ci = cm / 7;
        int co = m * 16 + (l & 15);
        int tap = (l >> 4) * 8 + j;
        float v = 0.f;
        if (co < COFF && tap < 27) v = w_off[(co * 67 + ci) * 27 + tap];
        pA[i] = f2bf(v);
    }
    for (int i = t0; i < 27 * 4 * 2 * 64 * 8; i += stride) {
        int jj = i & 7; int l = (i >> 3) & 63; int jf = (i >> 9) & 1;
        int w = (i >> 10) & 3; int k = i >> 12;
        int o = w * 16 + (l & 15);
        int c = jf * 32 + (l >> 4) * 8 + jj;
        pW[i] = f2bf(w_dcn[(o * 64 + c) * 27 + k]);
    }
}

// ---------------- kernel 1: offset conv via MFMA (no LDS, no barriers) ------
// per block: sp tile 64 (=2 h-rows), co 112 (7 m-tiles), K = 67 chunks of 32
__global__ __launch_bounds__(256, 1) void k_offset_conv(
    const float* __restrict__ x,
    const ushort* __restrict__ pA,
    const float* __restrict__ b_off,
    float* __restrict__ pred)
{
    const int bi = blockIdx.x;
    const int b = bi >> 7;
    const int spg = (bi & 127) * 64;
    const int d = spg >> 10;
    const int h0 = (spg >> 5) & 31;
    const int tid = threadIdx.x;
    const int wv = tid >> 6, lane = tid & 63, q = lane >> 4, r16 = lane & 15;
    const int spl = wv * 16 + r16;          // this lane's sp within tile (B col)
    const int h = h0 + (spl >> 5);
    const int w = spl & 31;

    // gather geometry: tap = q*8 + j, invariant across ci-chunks
    int xoff[8]; unsigned vmask = 0;
    #pragma unroll
    for (int j = 0; j < 8; ++j) {
        int tap = q * 8 + j;
        int dz = tap / 9, rem = tap - dz * 9, dy = rem / 3, dx = rem - dy * 3;
        int zz = d + dz - 1, yy = h + dy - 1, xx = w + dx - 1;
        bool ok = (tap < 27) && (zz >= 0) && (zz < DD) && (yy >= 0) && (yy < HHH)
                  && (xx >= 0) && (xx < WWW);
        xoff[j] = zz * 1024 + yy * 32 + xx;
        if (ok) vmask |= 1u << j;
    }

    f32x4 acc[7] = {};
    const float* __restrict__ xb = x + (size_t)b * CIN * DHW;

    for (int ci = 0; ci < 67; ++ci) {
        float v[8];
        if (ci < CIN) {
            const float* __restrict__ xc = xb + ci * DHW;
            #pragma unroll
            for (int j = 0; j < 8; ++j)
                v[j] = ((vmask >> j) & 1u) ? xc[xoff[j]] : 0.f;
        } else {
            #pragma unroll
            for (int j = 0; j < 8; ++j) {
                int tap = q * 8 + j;
                int dz = tap / 9, rem = tap - dz * 9, dy = rem / 3, dx = rem - dy * 3;
                float val;
                if (ci == 64)      val = -1.f + (2.f / 7.f)  * (float)(d + dz - 1);
                else if (ci == 65) val = -1.f + (2.f / 31.f) * (float)(h + dy - 1);
                else               val = -1.f + (2.f / 31.f) * (float)(w + dx - 1);
                v[j] = ((vmask >> j) & 1u) ? val : 0.f;
            }
        }
        bf16x8 bf;
        #pragma unroll
        for (int j = 0; j < 8; ++j) bf[j] = (short)f2bf(v[j]);

        #pragma unroll
        for (int m = 0; m < 7; ++m) {
            bf16x8 af = *(const bf16x8*)(pA + (size_t)((ci * 7 + m) * 64 + lane) * 8);
            acc[m] = __builtin_amdgcn_mfma_f32_16x16x32_bf16(af, bf, acc[m], 0, 0, 0);
        }
    }

    float* __restrict__ predb = pred + (size_t)b * COFF * DHW + spg;
    #pragma unroll
    for (int m = 0; m < 7; ++m) {
        #pragma unroll
        for (int r = 0; r < 4; ++r) {
            int co = m * 16 + q * 4 + r;
            if (co < COFF)
                predb[(size_t)co * DHW + spl] = acc[m][r] + b_off[co];
        }
    }
}

// ---------------- kernel 2: deformable sample (bf16 LDS) + MFMA -------------
// per block: sp tile 32 (one h-row), out 64 o; K = 27 chunks of 64 (c 0..63)
__global__ __launch_bounds__(256, 2) void k_dcn(
    const float* __restrict__ x,
    const float* __restrict__ pred,
    const ushort* __restrict__ pW,
    const float* __restrict__ b_dcn,
    float* __restrict__ out)
{
    __shared__ unsigned cw[27 * 32 * 8];     // 27648 B: (u16 idx)|(bf16 wgt*alpha)<<16
    __shared__ ushort S[2][32 * 64];         // 2 x 4096 B, XOR-swizzled [p][c]

    const int bi = blockIdx.x;
    const int b = bi >> 8;
    const int spg = (bi & 255) * 32;
    const int d = spg >> 10;
    const int h = (spg >> 5) & 31;
    const int tid = threadIdx.x;

    // ---- phase 0: all 27 corner tables ----
    const float* __restrict__ predb = pred + (size_t)b * COFF * DHW + spg;
    for (int kp = tid; kp < 27 * 32; kp += 256) {
        int k = kp >> 5, p = kp & 31;
        float offz = predb[(k * 3 + 0) * DHW + p];
        float offy = predb[(k * 3 + 1) * DHW + p];
        float offx = predb[(k * 3 + 2) * DHW + p];
        float av   = predb[(81 + k) * DHW + p];
        float alpha = 1.f / (1.f + expf(-av));
        int kz = k / 9, rem = k - kz * 9, ky = rem / 3, kx = rem - ky * 3;
        float pz = (float)(d + kz - 1) + offz;
        float py = (float)(h + ky - 1) + offy;
        float px = (float)(p + kx - 1) + offx;
        float fz = floorf(pz), fy = floorf(py), fx = floorf(px);
        float tz = pz - fz, ty = py - fy, tx = px - fx;
        int iz0 = (int)fz, iy0 = (int)fy, ix0 = (int)fx;
        #pragma unroll
        for (int c8 = 0; c8 < 8; ++c8) {
            int czi = c8 >> 2, cyi = (c8 >> 1) & 1, cxi = c8 & 1;
            int iz = iz0 + czi, iy = iy0 + cyi, ix = ix0 + cxi;
            float wz = czi ? tz : 1.f - tz;
            float wy = cyi ? ty : 1.f - ty;
            float wx = cxi ? tx : 1.f - tx;
            bool ok = (iz >= 0) && (iz < DD) && (iy >= 0) && (iy < HHH)
                      && (ix >= 0) && (ix < WWW);
            unsigned idx = ok ? (unsigned)(iz * 1024 + iy * 32 + ix) : 0u;
            float wgt = ok ? wz * wy * wx * alpha : 0.f;
            cw[kp * 8 + c8] = idx | ((unsigned)f2bf(wgt) << 16);
        }
    }
    __syncthreads();

    const int p = tid & 31, cg = tid >> 5;                 // sampling role
    const int wv = tid >> 6, lane = tid & 63, q = lane >> 4, r16 = lane & 15; // MFMA role
    const float* __restrict__ xc0 = x + (size_t)b * CIN * DHW + (size_t)cg * 8 * DHW;
    const unsigned swaddr = ((unsigned)(p * 128 + cg * 16)) ^ ((unsigned)(p & 7) << 4);
    f32x4 acc[2] = {};

    for (int k = 0; k < 27; ++k) {
        // ---- sample 8 channels for this (p) ----
        float sa[8] = {0.f, 0.f, 0.f, 0.f, 0.f, 0.f, 0.f, 0.f};
        const unsigned* __restrict__ cwp = &cw[(k * 32 + p) * 8];
        #pragma unroll
        for (int c8 = 0; c8 < 8; ++c8) {
            unsigned iw = cwp[c8];
            float wgt = __uint_as_float(iw & 0xffff0000u);
            unsigned idx = iw & 0xffffu;
            #pragma unroll
            for (int i = 0; i < 8; ++i)
                sa[i] += wgt * xc0[(size_t)i * DHW + idx];
        }
        uint4 pk;
        pk.x = (unsigned)f2bf(sa[0]) | ((unsigned)f2bf(sa[1]) << 16);
        pk.y = (unsigned)f2bf(sa[2]) | ((unsigned)f2bf(sa[3]) << 16);
        pk.z = (unsigned)f2bf(sa[4]) | ((unsigned)f2bf(sa[5]) << 16);
        pk.w = (unsigned)f2bf(sa[6]) | ((unsigned)f2bf(sa[7]) << 16);
        ushort* Sb = &S[k & 1][0];
        *(uint4*)((char*)Sb + swaddr) = pk;
        __syncthreads();

        // ---- MFMA: acc[pt] += W[o][c] * S[c][p] ----
        const ushort* __restrict__ pWk = pW + (size_t)k * 4096;
        #pragma unroll
        for (int jf = 0; jf < 2; ++jf) {
            bf16x8 af = *(const bf16x8*)(pWk + (size_t)(((wv * 2 + jf) * 64) + lane) * 8);
            #pragma unroll
            for (int pt = 0; pt < 2; ++pt) {
                int pp = pt * 16 + r16;
                unsigned baddr = ((unsigned)(pp * 128 + jf * 64 + q * 16))
                                 ^ ((unsigned)(pp & 7) << 4);
                bf16x8 bfv = *(const bf16x8*)((const char*)Sb + baddr);
                acc[pt] = __builtin_amdgcn_mfma_f32_16x16x32_bf16(af, bfv, acc[pt], 0, 0, 0);
            }
        }
    }

    float* __restrict__ ob = out + (size_t)b * COUT * DHW + spg;
    #pragma unroll
    for (int pt = 0; pt < 2; ++pt) {
        #pragma unroll
        for (int r = 0; r < 4; ++r) {
            int o = wv * 16 + q * 4 + r;
            ob[(size_t)o * DHW + pt * 16 + r16] = acc[pt][r] + b_dcn[o];
        }
    }
}

extern "C" void kernel_launch(void* const* d_in, const int* in_sizes, int n_in,
                              void* d_out, int out_size, void* d_ws, size_t ws_size,
                              hipStream_t stream) {
    const float* x     = (const float*)d_in[0];
    const float* w_off = (const float*)d_in[1];
    const float* b_off = (const float*)d_in[2];
    const float* w_dcn = (const float*)d_in[3];
    const float* b_dcn = (const float*)d_in[4];
    float* out = (float*)d_out;

    // workspace: pred fp32 [2][108][8192] | pA bf16 240128 | pW bf16 110592
    float*  pred = (float*)d_ws;                           // 7,077,888 B
    ushort* pA   = (ushort*)((char*)d_ws + 7077888);       //   480,256 B
    ushort* pW   = (ushort*)((char*)d_ws + 7558144);       //   221,184 B

    k_pack<<<256, 256, 0, stream>>>(w_off, w_dcn, pA, pW);
    k_offset_conv<<<256, 256, 0, stream>>>(x, pA, b_off, pred);
    k_dcn<<<512, 256, 0, stream>>>(x, pred, pW, b_dcn, out);
}

// Round 3
// 94.705 us; speedup vs baseline: 6.3398x; 3.2636x over previous
//
#include <hip/hip_runtime.h>

#define DHW  8192
#define CIN  64
#define COFF 108
#define COUT 64

typedef __attribute__((ext_vector_type(8))) short bf16x8;
typedef __attribute__((ext_vector_type(4))) float f32x4;

__device__ inline unsigned short f2bf(float f) {
    unsigned u = __float_as_uint(f);
    u += 0x7fffu + ((u >> 16) & 1u);     // RNE
    return (unsigned short)(u >> 16);
}
__device__ inline float bf2f(unsigned short h) {
    return __uint_as_float(((unsigned)h) << 16);
}

// ---------- kernel A: x [b][c][dhw] f32  ->  xt [b][dhw][c] bf16 (tiled) ----
__global__ __launch_bounds__(256) void k_xt(const float* __restrict__ x,
                                            ushort* __restrict__ xt)
{
    __shared__ ushort tile[64 * 66];
    const int bi = blockIdx.x;
    const int b  = bi >> 7;
    const int f0 = (bi & 127) * 64;
    const int tid = threadIdx.x;
    #pragma unroll
    for (int it = 0; it < 16; ++it) {
        int c = it * 4 + (tid >> 6);
        int f = tid & 63;
        float v = x[((size_t)(b * 64 + c)) * DHW + f0 + f];
        tile[f * 66 + c] = f2bf(v);
    }
    __syncthreads();
    #pragma unroll
    for (int it = 0; it < 16; ++it) {
        int f = it * 4 + (tid >> 6);
        int c = tid & 63;
        xt[((size_t)b * DHW + f0 + f) * 64 + c] = tile[f * 66 + c];
    }
}

// ---------- kernel B: pack weights into MFMA A-fragment order ----------------
// pA1[tap][ch][m][l][j] : co=m*16+(l&15), ci=ch*32+(l>>4)*8+j     (27*2*7*512)
// pAc[t][m][l][j]       : flatk=t*32+(l>>4)*8+j -> cc,tap          (3*7*512)
// pW [k][ch][m][l][j]   : o=m*16+(l&15), c=ch*32+(l>>4)*8+j       (27*2*4*512)
__global__ void k_pack(const float* __restrict__ w_off,
                       const float* __restrict__ w_dcn,
                       ushort* __restrict__ pA1,
                       ushort* __restrict__ pAc,
                       ushort* __restrict__ pW)
{
    int t0 = blockIdx.x * blockDim.x + threadIdx.x;
    int stride = gridDim.x * blockDim.x;
    for (int i = t0; i < 27 * 2 * 7 * 512; i += stride) {
        int j = i & 7, l = (i >> 3) & 63, rest = i >> 9;
        int m = rest % 7, ch = (rest / 7) & 1, tap = rest / 14;
        int co = m * 16 + (l & 15);
        int ci = ch * 32 + (l >> 4) * 8 + j;
        pA1[i] = (co < COFF) ? f2bf(w_off[(co * 67 + ci) * 27 + tap]) : (ushort)0;
    }
    for (int i = t0; i < 3 * 7 * 512; i += stride) {
        int j = i & 7, l = (i >> 3) & 63, rest = i >> 9;
        int m = rest % 7, t = rest / 7;
        int co = m * 16 + (l & 15);
        int flatk = t * 32 + (l >> 4) * 8 + j;
        ushort v = 0;
        if (co < COFF && flatk < 81) {
            int cc = flatk / 27, tap = flatk % 27;
            v = f2bf(w_off[(co * 67 + 64 + cc) * 27 + tap]);
        }
        pAc[i] = v;
    }
    for (int i = t0; i < 27 * 2 * 4 * 512; i += stride) {
        int j = i & 7, l = (i >> 3) & 63;
        int m = (i >> 9) & 3, ch = (i >> 11) & 1, k = i >> 12;
        int o = m * 16 + (l & 15);
        int c = ch * 32 + (l >> 4) * 8 + j;
        pW[i] = f2bf(w_dcn[(o * 64 + c) * 27 + k]);
    }
}

// ---------- kernel C: fused offset-conv -> corner tables -> sample+GEMM -----
// block: one (b, d, h) row of 32 sp; 4 waves: pt = wv&1 (p-tile), ch = wv>>1
__global__ __launch_bounds__(256, 2) void k_fused(
    const ushort* __restrict__ xt,
    const ushort* __restrict__ pA1,
    const ushort* __restrict__ pAc,
    const ushort* __restrict__ pW,
    const float* __restrict__ b_off,
    const float* __restrict__ b_dcn,
    float* __restrict__ out)
{
    __shared__ float    red[2 * 7 * 64 * 4];     // 14336 B (reused for stage-2)
    __shared__ float    pred_lds[COFF * 32];     // 13824 B
    __shared__ unsigned cw[27 * 32 * 8];         // 27648 B

    const int bi  = blockIdx.x;
    const int b   = bi >> 8;
    const int spg = (bi & 255) * 32;
    const int d   = spg >> 10;
    const int h   = (spg >> 5) & 31;
    const int tid = threadIdx.x;
    const int wv = tid >> 6, lane = tid & 63, q = lane >> 4, r16 = lane & 15;
    const int pt = wv & 1, ch = wv >> 1;
    const int p  = pt * 16 + r16;                // this lane's w coordinate
    const ushort* __restrict__ xb = xt + (size_t)b * DHW * 64;

    // ================= stage 1: offset conv (no barriers) =================
    f32x4 acc1[7] = {};
    #pragma unroll
    for (int tap = 0; tap < 27; ++tap) {
        const int dz = tap / 9, dy = (tap % 9) / 3, dx = tap % 3;
        const int zz = d + dz - 1, yy = h + dy - 1, xx = p + dx - 1;
        bool ok = ((unsigned)zz < 8u) & ((unsigned)yy < 32u) & ((unsigned)xx < 32u);
        bf16x8 bf = {};
        if (ok)
            bf = *(const bf16x8*)(xb + (size_t)((zz << 10) + (yy << 5) + xx) * 64
                                  + ch * 32 + q * 8);
        const ushort* pa = pA1 + (size_t)((tap * 2 + ch) * 7) * 512 + lane * 8;
        #pragma unroll
        for (int m = 0; m < 7; ++m)
            acc1[m] = __builtin_amdgcn_mfma_f32_16x16x32_bf16(
                *(const bf16x8*)(pa + m * 512), bf, acc1[m], 0, 0, 0);
    }
    // coord chunks: ch=0 -> t=0,1 ; ch=1 -> t=2
    const int nct = (ch == 0) ? 2 : 1;
    for (int ti = 0; ti < nct; ++ti) {
        const int t = (ch == 0) ? ti : 2;
        bf16x8 bf;
        #pragma unroll
        for (int j = 0; j < 8; ++j) {
            int flatk = t * 32 + q * 8 + j;
            int cc = flatk / 27, tap = flatk % 27;
            int dz = tap / 9, dy = (tap % 9) / 3, dx = tap % 3;
            int zz = d + dz - 1, yy = h + dy - 1, xx = p + dx - 1;
            bool ok = (flatk < 81) & ((unsigned)zz < 8u) & ((unsigned)yy < 32u)
                      & ((unsigned)xx < 32u);
            float val = 0.f;
            if (ok)
                val = (cc == 0) ? (-1.f + (2.f / 7.f) * (float)zz)
                    : (cc == 1) ? (-1.f + (2.f / 31.f) * (float)yy)
                                : (-1.f + (2.f / 31.f) * (float)xx);
            bf[j] = (short)f2bf(val);
        }
        const ushort* pa = pAc + (size_t)(t * 7) * 512 + lane * 8;
        #pragma unroll
        for (int m = 0; m < 7; ++m)
            acc1[m] = __builtin_amdgcn_mfma_f32_16x16x32_bf16(
                *(const bf16x8*)(pa + m * 512), bf, acc1[m], 0, 0, 0);
    }

    // cross-wave reduce (ch=1 -> ch=0), add bias, park pred in LDS
    if (ch == 1) {
        #pragma unroll
        for (int m = 0; m < 7; ++m)
            *(f32x4*)&red[(size_t)((pt * 7 + m) * 64 + lane) * 4] = acc1[m];
    }
    __syncthreads();
    if (ch == 0) {
        #pragma unroll
        for (int m = 0; m < 7; ++m) {
            f32x4 o = *(const f32x4*)&red[(size_t)((pt * 7 + m) * 64 + lane) * 4];
            #pragma unroll
            for (int r = 0; r < 4; ++r) {
                int co = m * 16 + q * 4 + r;
                if (co < COFF)
                    pred_lds[co * 32 + p] = acc1[m][r] + o[r] + b_off[co];
            }
        }
    }
    __syncthreads();

    // ================= corner tables =================
    for (int kp = tid; kp < 27 * 32; kp += 256) {
        int k = kp >> 5, pp = kp & 31;
        float offz = pred_lds[(k * 3 + 0) * 32 + pp];
        float offy = pred_lds[(k * 3 + 1) * 32 + pp];
        float offx = pred_lds[(k * 3 + 2) * 32 + pp];
        float av   = pred_lds[(81 + k) * 32 + pp];
        float alpha = 1.f / (1.f + expf(-av));
        int kz = k / 9, rem = k - kz * 9, ky = rem / 3, kx = rem - ky * 3;
        float pz = (float)(d + kz - 1) + offz;
        float py = (float)(h + ky - 1) + offy;
        float px = (float)(pp + kx - 1) + offx;
        float fz = floorf(pz), fy = floorf(py), fx = floorf(px);
        float tz = pz - fz, ty = py - fy, tx = px - fx;
        int iz0 = (int)fz, iy0 = (int)fy, ix0 = (int)fx;
        #pragma unroll
        for (int c8 = 0; c8 < 8; ++c8) {
            int czi = c8 >> 2, cyi = (c8 >> 1) & 1, cxi = c8 & 1;
            int iz = iz0 + czi, iy = iy0 + cyi, ix = ix0 + cxi;
            float wz = czi ? tz : 1.f - tz;
            float wy = cyi ? ty : 1.f - ty;
            float wx = cxi ? tx : 1.f - tx;
            bool okc = (iz >= 0) && (iz < 8) && (iy >= 0) && (iy < 32)
                       && (ix >= 0) && (ix < 32);
            unsigned idx = okc ? (unsigned)(iz * 1024 + iy * 32 + ix) : 0u;
            float wgt = okc ? wz * wy * wx * alpha : 0.f;
            cw[kp * 8 + c8] = idx | ((unsigned)f2bf(wgt) << 16);
        }
    }
    __syncthreads();

    // ================= stage 2: sample + GEMM (no barriers) =================
    f32x4 acc2[4] = {};
    const ushort* __restrict__ xbc = xb + ch * 32 + q * 8;
    #pragma unroll 3
    for (int k = 0; k < 27; ++k) {
        const unsigned* cwp = &cw[(k * 32 + p) * 8];
        uint4 c0 = *(const uint4*)(cwp);
        uint4 c1 = *(const uint4*)(cwp + 4);
        unsigned iws[8] = {c0.x, c0.y, c0.z, c0.w, c1.x, c1.y, c1.z, c1.w};
        float sa[8] = {};
        #pragma unroll
        for (int c8 = 0; c8 < 8; ++c8) {
            unsigned iw = iws[c8];
            float wgt = __uint_as_float(iw & 0xffff0000u);
            bf16x8 xv = *(const bf16x8*)(xbc + (size_t)(iw & 0xffffu) * 64);
            #pragma unroll
            for (int i = 0; i < 8; ++i)
                sa[i] += wgt * bf2f((unsigned short)xv[i]);
        }
        bf16x8 bfs;
        #pragma unroll
        for (int i = 0; i < 8; ++i) bfs[i] = (short)f2bf(sa[i]);
        const ushort* pw = pW + (size_t)((k * 2 + ch) * 4) * 512 + lane * 8;
        #pragma unroll
        for (int m = 0; m < 4; ++m)
            acc2[m] = __builtin_amdgcn_mfma_f32_16x16x32_bf16(
                *(const bf16x8*)(pw + m * 512), bfs, acc2[m], 0, 0, 0);
    }

    // cross-wave reduce + bias + store
    if (ch == 1) {
        #pragma unroll
        for (int m = 0; m < 4; ++m)
            *(f32x4*)&red[(size_t)((pt * 4 + m) * 64 + lane) * 4] = acc2[m];
    }
    __syncthreads();
    if (ch == 0) {
        float* __restrict__ ob = out + (size_t)b * COUT * DHW + spg;
        #pragma unroll
        for (int m = 0; m < 4; ++m) {
            f32x4 o2 = *(const f32x4*)&red[(size_t)((pt * 4 + m) * 64 + lane) * 4];
            #pragma unroll
            for (int r = 0; r < 4; ++r) {
                int oo = m * 16 + q * 4 + r;
                ob[(size_t)oo * DHW + p] = acc2[m][r] + o2[r] + b_dcn[oo];
            }
        }
    }
}

extern "C" void kernel_launch(void* const* d_in, const int* in_sizes, int n_in,
                              void* d_out, int out_size, void* d_ws, size_t ws_size,
                              hipStream_t stream) {
    const float* x     = (const float*)d_in[0];
    const float* w_off = (const float*)d_in[1];
    const float* b_off = (const float*)d_in[2];
    const float* w_dcn = (const float*)d_in[3];
    const float* b_dcn = (const float*)d_in[4];
    float* out = (float*)d_out;

    // workspace: xt bf16 [2][8192][64] | pA1 | pAc | pW
    ushort* xt  = (ushort*)d_ws;                          // 2,097,152 B
    ushort* pA1 = (ushort*)((char*)d_ws + 2097152);       //   387,072 B
    ushort* pAc = (ushort*)((char*)d_ws + 2484224);       //    21,504 B
    ushort* pW  = (ushort*)((char*)d_ws + 2505728);       //   221,184 B

    k_xt   <<<256, 256, 0, stream>>>(x, xt);
    k_pack <<<128, 256, 0, stream>>>(w_off, w_dcn, pA1, pAc, pW);
    k_fused<<<512, 256, 0, stream>>>(xt, pA1, pAc, pW, b_off, b_dcn, out);
}

// Round 4
// 89.370 us; speedup vs baseline: 6.7183x; 1.0597x over previous
//
#include <hip/hip_runtime.h>

#define DHW  8192
#define COFF 108

typedef __attribute__((ext_vector_type(8))) short bf16x8;
typedef __attribute__((ext_vector_type(4))) float f32x4;

__device__ inline unsigned short f2bf(float f) {
    unsigned u = __float_as_uint(f);
    u += 0x7fffu + ((u >> 16) & 1u);     // RNE
    return (unsigned short)(u >> 16);
}
__device__ inline float bf2f(unsigned short h) {
    return __uint_as_float(((unsigned)h) << 16);
}

// ---------------- kernel A: xt transpose + weight packing -------------------
// xt  [b][dhw][c] bf16
// pA1[(tap*2+ch)*7+m][l][j]: co=m*16+(l&15), ci=ch*32+(l>>4)*8+j
// pAc[t*7+m][l][j]:          flatk=t*32+(l>>4)*8+j -> (cc,tap)
// pW [(k*2+ch)*4+m][l][j]:   o=m*16+(l&15), c=ch*32+(l>>4)*8+j
__global__ __launch_bounds__(256) void k_prep(
    const float* __restrict__ x, const float* __restrict__ w_off,
    const float* __restrict__ w_dcn,
    ushort* __restrict__ xt, ushort* __restrict__ pA1,
    ushort* __restrict__ pAc, ushort* __restrict__ pW)
{
    __shared__ ushort tile[64 * 66];
    const int bi = blockIdx.x;
    const int tid = threadIdx.x;
    if (bi < 256) {
        const int b  = bi >> 7;
        const int f0 = (bi & 127) * 64;
        #pragma unroll
        for (int it = 0; it < 16; ++it) {
            int c = it * 4 + (tid >> 6), f = tid & 63;
            tile[f * 66 + c] = f2bf(x[((size_t)(b * 64 + c)) * DHW + f0 + f]);
        }
        __syncthreads();
        #pragma unroll
        for (int it = 0; it < 16; ++it) {
            int f = it * 4 + (tid >> 6), c = tid & 63;
            xt[((size_t)b * DHW + f0 + f) * 64 + c] = tile[f * 66 + c];
        }
    } else {
        int t0 = (bi - 256) * 256 + tid;
        const int stride = 32 * 256;
        for (int i = t0; i < 27 * 2 * 7 * 512; i += stride) {
            int j = i & 7, l = (i >> 3) & 63, rest = i >> 9;
            int m = rest % 7, ch = (rest / 7) & 1, tap = rest / 14;
            int co = m * 16 + (l & 15);
            int ci = ch * 32 + (l >> 4) * 8 + j;
            pA1[i] = (co < COFF) ? f2bf(w_off[(co * 67 + ci) * 27 + tap]) : (ushort)0;
        }
        for (int i = t0; i < 3 * 7 * 512; i += stride) {
            int j = i & 7, l = (i >> 3) & 63, rest = i >> 9;
            int m = rest % 7, t = rest / 7;
            int co = m * 16 + (l & 15);
            int flatk = t * 32 + (l >> 4) * 8 + j;
            ushort v = 0;
            if (co < COFF && flatk < 81) {
                int cc = flatk / 27, tap = flatk % 27;
                v = f2bf(w_off[(co * 67 + 64 + cc) * 27 + tap]);
            }
            pAc[i] = v;
        }
        for (int i = t0; i < 27 * 2 * 4 * 512; i += stride) {
            int j = i & 7, l = (i >> 3) & 63;
            int m = (i >> 9) & 3, ch = (i >> 11) & 1, k = i >> 12;
            int o = m * 16 + (l & 15);
            int c = ch * 32 + (l >> 4) * 8 + j;
            pW[i] = f2bf(w_dcn[(o * 64 + c) * 27 + k]);
        }
    }
}

// ---------------- kernel B: fused conv -> corners -> sample+GEMM ------------
// block: 32 sp (one h-row), 4 waves = 4-way K-split, pt-in-wave (2 sp-tiles)
__global__ __launch_bounds__(256, 2) void k_fused(
    const ushort* __restrict__ xt, const ushort* __restrict__ pA1,
    const ushort* __restrict__ pAc, const ushort* __restrict__ pW,
    const float* __restrict__ b_off, const float* __restrict__ b_dcn,
    float* __restrict__ out)
{
    __shared__ __align__(16) char smem[49920];
    ushort* pred_lds = (ushort*)smem;            // 6912 B  bf16 [108][32]
    char*   region   = smem + 6912;              // 43008 B union:
    // red1: f32x4[(w1*14+i)*64+lane]            (43008 B)
    // cwi : uint4[(k*2+half)*32+p]              (27648 B)   pre-shifted byte idx
    // cww : uint4[k*32+p] at +27648             (13824 B)   8 packed bf16 wgts
    // red2: f32x4[(wv*8+i)*64+lane]             (32768 B)

    const int bi  = blockIdx.x;
    const int b   = bi >> 8;
    const int spg = (bi & 255) * 32;
    const int d   = spg >> 10;
    const int h   = (spg >> 5) & 31;
    const int tid = threadIdx.x;
    const int wv = tid >> 6, lane = tid & 63, q = lane >> 4, r16 = lane & 15;
    const ushort* __restrict__ xb = xt + (size_t)b * DHW * 64;

    // ===== stage 1: offset conv, 57 K-chunks interleaved over 4 waves =====
    f32x4 acc1[14] = {};      // i = m*2 + pt
    for (int c = wv; c < 57; c += 4) {
        bf16x8 bfv[2];
        const ushort* pa;
        if (c < 54) {
            int tap = c >> 1, ch = c & 1;
            int dz = tap / 9, rem9 = tap - dz * 9, dy = rem9 / 3, dx = rem9 - dy * 3;
            int zz = d + dz - 1, yy = h + dy - 1;
            int basepos = (zz << 10) + (yy << 5);
            bool okzy = ((unsigned)zz < 8u) & ((unsigned)yy < 32u);
            #pragma unroll
            for (int pt = 0; pt < 2; ++pt) {
                int xx = pt * 16 + r16 + dx - 1;
                bool ok = okzy & ((unsigned)xx < 32u);
                bf16x8 t = {};
                if (ok) t = *(const bf16x8*)(xb + (size_t)(basepos + xx) * 64 + ch * 32 + q * 8);
                bfv[pt] = t;
            }
            pa = pA1 + (size_t)((tap * 2 + ch) * 7) * 512 + lane * 8;
        } else {
            int t = c - 54;
            #pragma unroll
            for (int pt = 0; pt < 2; ++pt) {
                bf16x8 bt;
                #pragma unroll
                for (int j = 0; j < 8; ++j) {
                    int flatk = t * 32 + q * 8 + j;
                    int cc = flatk / 27, tap = flatk % 27;
                    int dz = tap / 9, rem9 = tap - dz * 9, dy = rem9 / 3, dx = rem9 - dy * 3;
                    int zz = d + dz - 1, yy = h + dy - 1, xx = pt * 16 + r16 + dx - 1;
                    bool ok = (flatk < 81) & ((unsigned)zz < 8u) & ((unsigned)yy < 32u)
                              & ((unsigned)xx < 32u);
                    float val = 0.f;
                    if (ok)
                        val = (cc == 0) ? (-1.f + (2.f / 7.f) * (float)zz)
                            : (cc == 1) ? (-1.f + (2.f / 31.f) * (float)yy)
                                        : (-1.f + (2.f / 31.f) * (float)xx);
                    bt[j] = (short)f2bf(val);
                }
                bfv[pt] = bt;
            }
            pa = pAc + (size_t)(t * 7) * 512 + lane * 8;
        }
        #pragma unroll
        for (int m = 0; m < 7; ++m) {
            bf16x8 af = *(const bf16x8*)(pa + m * 512);
            acc1[m * 2 + 0] = __builtin_amdgcn_mfma_f32_16x16x32_bf16(af, bfv[0], acc1[m * 2 + 0], 0, 0, 0);
            acc1[m * 2 + 1] = __builtin_amdgcn_mfma_f32_16x16x32_bf16(af, bfv[1], acc1[m * 2 + 1], 0, 0, 0);
        }
    }
    if (wv) {
        f32x4* red1 = (f32x4*)region;
        #pragma unroll
        for (int i = 0; i < 14; ++i)
            red1[((wv - 1) * 14 + i) * 64 + lane] = acc1[i];
    }
    __syncthreads();
    if (wv == 0) {
        const f32x4* red1 = (const f32x4*)region;
        #pragma unroll
        for (int i = 0; i < 14; ++i) {
            f32x4 s = acc1[i];
            #pragma unroll
            for (int w1 = 0; w1 < 3; ++w1)
                s += red1[(w1 * 14 + i) * 64 + lane];
            int m = i >> 1, pt = i & 1;
            #pragma unroll
            for (int r = 0; r < 4; ++r) {
                int co = m * 16 + q * 4 + r;
                if (co < COFF)
                    pred_lds[co * 32 + pt * 16 + r16] = f2bf(s[r] + b_off[co]);
            }
        }
    }
    __syncthreads();

    // ===== corner tables =====
    uint4* cwi = (uint4*)region;
    uint4* cww = (uint4*)(region + 27648);
    for (int kp = tid; kp < 27 * 32; kp += 256) {
        int k = kp >> 5, p = kp & 31;
        float offz = bf2f(pred_lds[(k * 3 + 0) * 32 + p]);
        float offy = bf2f(pred_lds[(k * 3 + 1) * 32 + p]);
        float offx = bf2f(pred_lds[(k * 3 + 2) * 32 + p]);
        float av   = bf2f(pred_lds[(81 + k) * 32 + p]);
        float alpha = 1.f / (1.f + __expf(-av));
        int kz = k / 9, rem = k - kz * 9, ky = rem / 3, kx = rem - ky * 3;
        float pz = (float)(d + kz - 1) + offz;
        float py = (float)(h + ky - 1) + offy;
        float px = (float)(p + kx - 1) + offx;
        float fz = floorf(pz), fy = floorf(py), fx = floorf(px);
        float tz = pz - fz, ty = py - fy, tx = px - fx;
        int iz0 = (int)fz, iy0 = (int)fy, ix0 = (int)fx;
        unsigned idxs[8]; float wgts[8];
        #pragma unroll
        for (int c8 = 0; c8 < 8; ++c8) {
            int czi = c8 >> 2, cyi = (c8 >> 1) & 1, cxi = c8 & 1;
            int iz = iz0 + czi, iy = iy0 + cyi, ix = ix0 + cxi;
            float wz = czi ? tz : 1.f - tz;
            float wy = cyi ? ty : 1.f - ty;
            float wx = cxi ? tx : 1.f - tx;
            bool ok = ((unsigned)iz < 8u) && ((unsigned)iy < 32u) && ((unsigned)ix < 32u);
            idxs[c8] = ok ? ((unsigned)((iz << 10) + (iy << 5) + ix) << 7) : 0u;
            wgts[c8] = ok ? wz * wy * wx * alpha : 0.f;
        }
        cwi[(k * 2 + 0) * 32 + p] = make_uint4(idxs[0], idxs[1], idxs[2], idxs[3]);
        cwi[(k * 2 + 1) * 32 + p] = make_uint4(idxs[4], idxs[5], idxs[6], idxs[7]);
        cww[k * 32 + p] = make_uint4(
            (unsigned)f2bf(wgts[0]) | ((unsigned)f2bf(wgts[1]) << 16),
            (unsigned)f2bf(wgts[2]) | ((unsigned)f2bf(wgts[3]) << 16),
            (unsigned)f2bf(wgts[4]) | ((unsigned)f2bf(wgts[5]) << 16),
            (unsigned)f2bf(wgts[6]) | ((unsigned)f2bf(wgts[7]) << 16));
    }
    __syncthreads();

    // ===== stage 2: sample + GEMM, (ch, k-half) per wave, pt-in-wave =====
    const int ch = wv & 1, kh = wv >> 1;
    const int kbeg = kh ? 14 : 0, kend = kh ? 27 : 14;
    f32x4 acc2[8] = {};     // i = m*2 + pt
    const char* xbcB = (const char*)xb + (ch * 32 + q * 8) * 2;
    for (int k = kbeg; k < kend; ++k) {
        bf16x8 bfs[2];
        #pragma unroll
        for (int pt = 0; pt < 2; ++pt) {
            int p = pt * 16 + r16;
            uint4 wq = cww[k * 32 + p];
            uint4 i0 = cwi[(k * 2 + 0) * 32 + p];
            uint4 i1 = cwi[(k * 2 + 1) * 32 + p];
            unsigned iv[8] = {i0.x, i0.y, i0.z, i0.w, i1.x, i1.y, i1.z, i1.w};
            unsigned wp[4] = {wq.x, wq.y, wq.z, wq.w};
            float sa[8] = {};
            #pragma unroll
            for (int cp = 0; cp < 4; ++cp) {
                float wlo = __uint_as_float(wp[cp] << 16);
                float whi = __uint_as_float(wp[cp] & 0xffff0000u);
                uint4 xa = *(const uint4*)(xbcB + iv[cp * 2 + 0]);
                uint4 xc = *(const uint4*)(xbcB + iv[cp * 2 + 1]);
                unsigned ua[4] = {xa.x, xa.y, xa.z, xa.w};
                unsigned ub[4] = {xc.x, xc.y, xc.z, xc.w};
                #pragma unroll
                for (int dw = 0; dw < 4; ++dw) {
                    sa[dw * 2 + 0] += wlo * __uint_as_float(ua[dw] << 16);
                    sa[dw * 2 + 1] += wlo * __uint_as_float(ua[dw] & 0xffff0000u);
                    sa[dw * 2 + 0] += whi * __uint_as_float(ub[dw] << 16);
                    sa[dw * 2 + 1] += whi * __uint_as_float(ub[dw] & 0xffff0000u);
                }
            }
            bf16x8 bt;
            #pragma unroll
            for (int j = 0; j < 8; ++j) bt[j] = (short)f2bf(sa[j]);
            bfs[pt] = bt;
        }
        const ushort* pwk = pW + (size_t)((k * 2 + ch) * 4) * 512 + lane * 8;
        #pragma unroll
        for (int m = 0; m < 4; ++m) {
            bf16x8 af = *(const bf16x8*)(pwk + m * 512);
            acc2[m * 2 + 0] = __builtin_amdgcn_mfma_f32_16x16x32_bf16(af, bfs[0], acc2[m * 2 + 0], 0, 0, 0);
            acc2[m * 2 + 1] = __builtin_amdgcn_mfma_f32_16x16x32_bf16(af, bfs[1], acc2[m * 2 + 1], 0, 0, 0);
        }
    }

    __syncthreads();   // cw dead only after ALL waves finish their k-loop
    f32x4* red2 = (f32x4*)region;
    #pragma unroll
    for (int i = 0; i < 8; ++i)
        red2[(wv * 8 + i) * 64 + lane] = acc2[i];
    __syncthreads();
    // wave wv combines m = wv (both pt tiles)
    float* __restrict__ outb = out + (size_t)b * 64 * DHW + spg;
    #pragma unroll
    for (int pt = 0; pt < 2; ++pt) {
        int i = wv * 2 + pt;
        f32x4 s = red2[i * 64 + lane];
        #pragma unroll
        for (int w1 = 1; w1 < 4; ++w1)
            s += red2[(w1 * 8 + i) * 64 + lane];
        #pragma unroll
        for (int r = 0; r < 4; ++r) {
            int o = wv * 16 + q * 4 + r;
            outb[(size_t)o * DHW + pt * 16 + r16] = s[r] + b_dcn[o];
        }
    }
}

extern "C" void kernel_launch(void* const* d_in, const int* in_sizes, int n_in,
                              void* d_out, int out_size, void* d_ws, size_t ws_size,
                              hipStream_t stream) {
    const float* x     = (const float*)d_in[0];
    const float* w_off = (const float*)d_in[1];
    const float* b_off = (const float*)d_in[2];
    const float* w_dcn = (const float*)d_in[3];
    const float* b_dcn = (const float*)d_in[4];
    float* out = (float*)d_out;

    ushort* xt  = (ushort*)d_ws;                          // 2,097,152 B
    ushort* pA1 = (ushort*)((char*)d_ws + 2097152);       //   387,072 B
    ushort* pAc = (ushort*)((char*)d_ws + 2484224);       //    21,504 B
    ushort* pW  = (ushort*)((char*)d_ws + 2505728);       //   221,184 B

    k_prep <<<288, 256, 0, stream>>>(x, w_off, w_dcn, xt, pA1, pAc, pW);
    k_fused<<<512, 256, 0, stream>>>(xt, pA1, pAc, pW, b_off, b_dcn, out);
}

// Round 5
// 86.931 us; speedup vs baseline: 6.9068x; 1.0281x over previous
//
#include <hip/hip_runtime.h>

#define DHW  8192
#define COFF 108

typedef __attribute__((ext_vector_type(8))) short bf16x8;
typedef __attribute__((ext_vector_type(4))) float f32x4;
typedef __bf16 bfv2 __attribute__((ext_vector_type(2)));

__device__ inline unsigned short f2bf(float f) {
    unsigned u = __float_as_uint(f);
    u += 0x7fffu + ((u >> 16) & 1u);     // RNE
    return (unsigned short)(u >> 16);
}
__device__ inline float bf2f(unsigned short h) {
    return __uint_as_float(((unsigned)h) << 16);
}

// dot2: c += a.lo*b.lo + a.hi*b.hi  (bf16 pairs packed in dwords)
__device__ inline float dot2bf(unsigned a, unsigned b, float c) {
#if defined(__has_builtin) && __has_builtin(__builtin_amdgcn_fdot2_f32_bf16)
    return __builtin_amdgcn_fdot2_f32_bf16(__builtin_bit_cast(bfv2, a),
                                           __builtin_bit_cast(bfv2, b), c, false);
#else
    c += __uint_as_float(a << 16) * __uint_as_float(b << 16);
    c += __uint_as_float(a & 0xffff0000u) * __uint_as_float(b & 0xffff0000u);
    return c;
#endif
}

// ---------------- kernel A: xt transpose + weight packing -------------------
// xt  [b][dhw][c] bf16
// pA1[(tap*2+ch)*7+m][l][j]: co=m*16+(l&15), ci=ch*32+(l>>4)*8+j
// pAc[t*7+m][l][j]:          flatk=t*32+(l>>4)*8+j -> (cc,tap)
// pW [(k*2+ch)*4+m][l][j]:   o=m*16+(l&15), c=ch*32+(l>>4)*8+j
__global__ __launch_bounds__(256) void k_prep(
    const float* __restrict__ x, const float* __restrict__ w_off,
    const float* __restrict__ w_dcn,
    ushort* __restrict__ xt, ushort* __restrict__ pA1,
    ushort* __restrict__ pAc, ushort* __restrict__ pW)
{
    __shared__ ushort tile[16 * 66];
    const int bi = blockIdx.x;
    const int tid = threadIdx.x;
    if (bi < 1024) {
        const int b  = bi >> 9;
        const int f0 = (bi & 511) * 16;
        #pragma unroll
        for (int it = 0; it < 4; ++it) {
            int c = it * 16 + (tid >> 4), f = tid & 15;
            tile[f * 66 + c] = f2bf(x[((size_t)(b * 64 + c)) * DHW + f0 + f]);
        }
        __syncthreads();
        #pragma unroll
        for (int it = 0; it < 4; ++it) {
            int f = it * 4 + (tid >> 6), c = tid & 63;
            xt[((size_t)b * DHW + f0 + f) * 64 + c] = tile[f * 66 + c];
        }
    } else {
        int t0 = (bi - 1024) * 256 + tid;
        const int stride = 32 * 256;
        for (int i = t0; i < 27 * 2 * 7 * 512; i += stride) {
            int j = i & 7, l = (i >> 3) & 63, rest = i >> 9;
            int m = rest % 7, ch = (rest / 7) & 1, tap = rest / 14;
            int co = m * 16 + (l & 15);
            int ci = ch * 32 + (l >> 4) * 8 + j;
            pA1[i] = (co < COFF) ? f2bf(w_off[(co * 67 + ci) * 27 + tap]) : (ushort)0;
        }
        for (int i = t0; i < 3 * 7 * 512; i += stride) {
            int j = i & 7, l = (i >> 3) & 63, rest = i >> 9;
            int m = rest % 7, t = rest / 7;
            int co = m * 16 + (l & 15);
            int flatk = t * 32 + (l >> 4) * 8 + j;
            ushort v = 0;
            if (co < COFF && flatk < 81) {
                int cc = flatk / 27, tap = flatk % 27;
                v = f2bf(w_off[(co * 67 + 64 + cc) * 27 + tap]);
            }
            pAc[i] = v;
        }
        for (int i = t0; i < 27 * 2 * 4 * 512; i += stride) {
            int j = i & 7, l = (i >> 3) & 63;
            int m = (i >> 9) & 3, ch = (i >> 11) & 1, k = i >> 12;
            int o = m * 16 + (l & 15);
            int c = ch * 32 + (l >> 4) * 8 + j;
            pW[i] = f2bf(w_dcn[(o * 64 + c) * 27 + k]);
        }
    }
}

// ---------------- kernel B: fused conv -> corners -> sample+GEMM ------------
// block: 16 sp (half h-row), 4 waves = 4-way K-split
__global__ __launch_bounds__(256, 4) void k_fused(
    const ushort* __restrict__ xt, const ushort* __restrict__ pA1,
    const ushort* __restrict__ pAc, const ushort* __restrict__ pW,
    const float* __restrict__ b_off, const float* __restrict__ b_dcn,
    float* __restrict__ out)
{
    __shared__ __align__(16) char smem[24960];
    ushort* pred_lds = (ushort*)smem;            // 3456 B  bf16 [108][16]
    char*   region   = smem + 3456;              // 21504 B union:
    // red1: f32x4[(w1*7+m)*64+lane]             (21504 B)
    // cwi : uint4[(k*2+half)*16+p]              (13824 B)   pre-shifted byte idx
    // cww : uint4[k*16+p] at +13824             ( 6912 B)   8 packed bf16 wgts
    // red2: f32x4[(wv*4+m)*64+lane]             (16384 B)

    const int bi   = blockIdx.x;
    const int b    = bi >> 9;
    const int sp16 = bi & 511;
    const int spg  = sp16 * 16;
    const int d    = sp16 >> 6;
    const int h    = (sp16 >> 1) & 31;
    const int w0   = (sp16 & 1) * 16;
    const int tid = threadIdx.x;
    const int wv = tid >> 6, lane = tid & 63, q = lane >> 4, r16 = lane & 15;
    const ushort* __restrict__ xb = xt + (size_t)b * DHW * 64;

    // ===== stage 1: offset conv, 57 K-chunks interleaved over 4 waves =====
    f32x4 acc1[7] = {};
    for (int c = wv; c < 57; c += 4) {
        bf16x8 bf = {};
        const ushort* pa;
        if (c < 54) {
            int tap = c >> 1, ch = c & 1;
            int dz = tap / 9, rem9 = tap - dz * 9, dy = rem9 / 3, dx = rem9 - dy * 3;
            int zz = d + dz - 1, yy = h + dy - 1, xx = w0 + r16 + dx - 1;
            bool ok = ((unsigned)zz < 8u) & ((unsigned)yy < 32u) & ((unsigned)xx < 32u);
            if (ok)
                bf = *(const bf16x8*)(xb + (size_t)((zz << 10) + (yy << 5) + xx) * 64
                                      + ch * 32 + q * 8);
            pa = pA1 + (size_t)((tap * 2 + ch) * 7) * 512 + lane * 8;
        } else {
            int t = c - 54;
            #pragma unroll
            for (int j = 0; j < 8; ++j) {
                int flatk = t * 32 + q * 8 + j;
                int cc = flatk / 27, tap = flatk % 27;
                int dz = tap / 9, rem9 = tap - dz * 9, dy = rem9 / 3, dx = rem9 - dy * 3;
                int zz = d + dz - 1, yy = h + dy - 1, xx = w0 + r16 + dx - 1;
                bool ok = (flatk < 81) & ((unsigned)zz < 8u) & ((unsigned)yy < 32u)
                          & ((unsigned)xx < 32u);
                float val = 0.f;
                if (ok)
                    val = (cc == 0) ? (-1.f + (2.f / 7.f) * (float)zz)
                        : (cc == 1) ? (-1.f + (2.f / 31.f) * (float)yy)
                                    : (-1.f + (2.f / 31.f) * (float)xx);
                bf[j] = (short)f2bf(val);
            }
            pa = pAc + (size_t)(t * 7) * 512 + lane * 8;
        }
        #pragma unroll
        for (int m = 0; m < 7; ++m)
            acc1[m] = __builtin_amdgcn_mfma_f32_16x16x32_bf16(
                *(const bf16x8*)(pa + m * 512), bf, acc1[m], 0, 0, 0);
    }
    if (wv) {
        f32x4* red1 = (f32x4*)region;
        #pragma unroll
        for (int m = 0; m < 7; ++m)
            red1[((wv - 1) * 7 + m) * 64 + lane] = acc1[m];
    }
    __syncthreads();
    if (wv == 0) {
        const f32x4* red1 = (const f32x4*)region;
        #pragma unroll
        for (int m = 0; m < 7; ++m) {
            f32x4 s = acc1[m];
            #pragma unroll
            for (int w1 = 0; w1 < 3; ++w1)
                s += red1[(w1 * 7 + m) * 64 + lane];
            #pragma unroll
            for (int r = 0; r < 4; ++r) {
                int co = m * 16 + q * 4 + r;
                if (co < COFF)
                    pred_lds[co * 16 + r16] = f2bf(s[r] + b_off[co]);
            }
        }
    }
    __syncthreads();

    // ===== corner tables =====
    uint4* cwi = (uint4*)region;
    uint4* cww = (uint4*)(region + 13824);
    for (int kp = tid; kp < 27 * 16; kp += 256) {
        int k = kp >> 4, p = kp & 15;
        float offz = bf2f(pred_lds[(k * 3 + 0) * 16 + p]);
        float offy = bf2f(pred_lds[(k * 3 + 1) * 16 + p]);
        float offx = bf2f(pred_lds[(k * 3 + 2) * 16 + p]);
        float av   = bf2f(pred_lds[(81 + k) * 16 + p]);
        float alpha = 1.f / (1.f + __expf(-av));
        int kz = k / 9, rem = k - kz * 9, ky = rem / 3, kx = rem - ky * 3;
        float pz = (float)(d + kz - 1) + offz;
        float py = (float)(h + ky - 1) + offy;
        float px = (float)(w0 + p + kx - 1) + offx;
        float fz = floorf(pz), fy = floorf(py), fx = floorf(px);
        float tz = pz - fz, ty = py - fy, tx = px - fx;
        int iz0 = (int)fz, iy0 = (int)fy, ix0 = (int)fx;
        unsigned idxs[8]; float wgts[8];
        #pragma unroll
        for (int c8 = 0; c8 < 8; ++c8) {
            int czi = c8 >> 2, cyi = (c8 >> 1) & 1, cxi = c8 & 1;
            int iz = iz0 + czi, iy = iy0 + cyi, ix = ix0 + cxi;
            float wz = czi ? tz : 1.f - tz;
            float wy = cyi ? ty : 1.f - ty;
            float wx = cxi ? tx : 1.f - tx;
            bool ok = ((unsigned)iz < 8u) && ((unsigned)iy < 32u) && ((unsigned)ix < 32u);
            idxs[c8] = ok ? ((unsigned)((iz << 10) + (iy << 5) + ix) << 7) : 0u;
            wgts[c8] = ok ? wz * wy * wx * alpha : 0.f;
        }
        cwi[(k * 2 + 0) * 16 + p] = make_uint4(idxs[0], idxs[1], idxs[2], idxs[3]);
        cwi[(k * 2 + 1) * 16 + p] = make_uint4(idxs[4], idxs[5], idxs[6], idxs[7]);
        cww[k * 16 + p] = make_uint4(
            (unsigned)f2bf(wgts[0]) | ((unsigned)f2bf(wgts[1]) << 16),
            (unsigned)f2bf(wgts[2]) | ((unsigned)f2bf(wgts[3]) << 16),
            (unsigned)f2bf(wgts[4]) | ((unsigned)f2bf(wgts[5]) << 16),
            (unsigned)f2bf(wgts[6]) | ((unsigned)f2bf(wgts[7]) << 16));
    }
    __syncthreads();

    // ===== stage 2: sample (dot2) + GEMM, (ch, k-half) per wave =====
    const int ch = wv & 1, kh = wv >> 1;
    const int kbeg = kh ? 14 : 0, kend = kh ? 27 : 14;
    f32x4 acc2[4] = {};
    const char* xbcB = (const char*)xb + (ch * 32 + q * 8) * 2;
    for (int k = kbeg; k < kend; ++k) {
        uint4 wq = cww[k * 16 + r16];
        uint4 i0 = cwi[(k * 2 + 0) * 16 + r16];
        uint4 i1 = cwi[(k * 2 + 1) * 16 + r16];
        unsigned iv[8] = {i0.x, i0.y, i0.z, i0.w, i1.x, i1.y, i1.z, i1.w};
        unsigned wp[4] = {wq.x, wq.y, wq.z, wq.w};
        float sa[8] = {};
        #pragma unroll
        for (int pr = 0; pr < 4; ++pr) {
            uint4 xa = *(const uint4*)(xbcB + iv[pr * 2 + 0]);
            uint4 xc = *(const uint4*)(xbcB + iv[pr * 2 + 1]);
            unsigned ua[4] = {xa.x, xa.y, xa.z, xa.w};
            unsigned ub[4] = {xc.x, xc.y, xc.z, xc.w};
            #pragma unroll
            for (int dw = 0; dw < 4; ++dw) {
                unsigned plo = __builtin_amdgcn_perm(ub[dw], ua[dw], 0x05040100u);
                unsigned phi = __builtin_amdgcn_perm(ub[dw], ua[dw], 0x07060302u);
                sa[dw * 2 + 0] = dot2bf(plo, wp[pr], sa[dw * 2 + 0]);
                sa[dw * 2 + 1] = dot2bf(phi, wp[pr], sa[dw * 2 + 1]);
            }
        }
        bf16x8 bfs;
        #pragma unroll
        for (int j = 0; j < 8; ++j) bfs[j] = (short)f2bf(sa[j]);
        const ushort* pwk = pW + (size_t)((k * 2 + ch) * 4) * 512 + lane * 8;
        #pragma unroll
        for (int m = 0; m < 4; ++m)
            acc2[m] = __builtin_amdgcn_mfma_f32_16x16x32_bf16(
                *(const bf16x8*)(pwk + m * 512), bfs, acc2[m], 0, 0, 0);
    }

    __syncthreads();   // cw dead only after ALL waves finish their k-loop
    f32x4* red2 = (f32x4*)region;
    #pragma unroll
    for (int m = 0; m < 4; ++m)
        red2[(wv * 4 + m) * 64 + lane] = acc2[m];
    __syncthreads();
    // wave wv combines m = wv
    float* __restrict__ outb = out + (size_t)b * 64 * DHW + spg;
    f32x4 s = red2[(0 * 4 + wv) * 64 + lane];
    #pragma unroll
    for (int w1 = 1; w1 < 4; ++w1)
        s += red2[(w1 * 4 + wv) * 64 + lane];
    #pragma unroll
    for (int r = 0; r < 4; ++r) {
        int o = wv * 16 + q * 4 + r;
        outb[(size_t)o * DHW + r16] = s[r] + b_dcn[o];
    }
}

extern "C" void kernel_launch(void* const* d_in, const int* in_sizes, int n_in,
                              void* d_out, int out_size, void* d_ws, size_t ws_size,
                              hipStream_t stream) {
    const float* x     = (const float*)d_in[0];
    const float* w_off = (const float*)d_in[1];
    const float* b_off = (const float*)d_in[2];
    const float* w_dcn = (const float*)d_in[3];
    const float* b_dcn = (const float*)d_in[4];
    float* out = (float*)d_out;

    ushort* xt  = (ushort*)d_ws;                          // 2,097,152 B
    ushort* pA1 = (ushort*)((char*)d_ws + 2097152);       //   387,072 B
    ushort* pAc = (ushort*)((char*)d_ws + 2484224);       //    21,504 B
    ushort* pW  = (ushort*)((char*)d_ws + 2505728);       //   221,184 B

    k_prep <<<1056, 256, 0, stream>>>(x, w_off, w_dcn, xt, pA1, pAc, pW);
    k_fused<<<1024, 256, 0, stream>>>(xt, pA1, pAc, pW, b_off, b_dcn, out);
}

// Round 6
// 61.528 us; speedup vs baseline: 9.7584x; 1.4129x over previous
//
#include <hip/hip_runtime.h>

#define DHW  8192
#define COFF 108

typedef __attribute__((ext_vector_type(8))) short bf16x8;
typedef __attribute__((ext_vector_type(4))) float f32x4;
typedef __bf16 bfv2 __attribute__((ext_vector_type(2)));

__device__ inline unsigned short f2bf(float f) {
    unsigned u = __float_as_uint(f);
    u += 0x7fffu + ((u >> 16) & 1u);     // RNE
    return (unsigned short)(u >> 16);
}
__device__ inline float bf2f(unsigned short h) {
    return __uint_as_float(((unsigned)h) << 16);
}

// dot2: c += a.lo*b.lo + a.hi*b.hi  (bf16 pairs packed in dwords)
__device__ inline float dot2bf(unsigned a, unsigned b, float c) {
#if defined(__has_builtin) && __has_builtin(__builtin_amdgcn_fdot2_f32_bf16)
    return __builtin_amdgcn_fdot2_f32_bf16(__builtin_bit_cast(bfv2, a),
                                           __builtin_bit_cast(bfv2, b), c, false);
#else
    c += __uint_as_float(a << 16) * __uint_as_float(b << 16);
    c += __uint_as_float(a & 0xffff0000u) * __uint_as_float(b & 0xffff0000u);
    return c;
#endif
}

// ---------------- kernel A: xt transpose + weight packing -------------------
__global__ __launch_bounds__(256) void k_prep(
    const float* __restrict__ x, const float* __restrict__ w_off,
    const float* __restrict__ w_dcn,
    ushort* __restrict__ xt, ushort* __restrict__ pA1,
    ushort* __restrict__ pAc, ushort* __restrict__ pW)
{
    __shared__ ushort tile[16 * 66];
    const int bi = blockIdx.x;
    const int tid = threadIdx.x;
    if (bi < 1024) {
        const int b  = bi >> 9;
        const int f0 = (bi & 511) * 16;
        #pragma unroll
        for (int it = 0; it < 4; ++it) {
            int c = it * 16 + (tid >> 4), f = tid & 15;
            tile[f * 66 + c] = f2bf(x[((size_t)(b * 64 + c)) * DHW + f0 + f]);
        }
        __syncthreads();
        #pragma unroll
        for (int it = 0; it < 4; ++it) {
            int f = it * 4 + (tid >> 6), c = tid & 63;
            xt[((size_t)b * DHW + f0 + f) * 64 + c] = tile[f * 66 + c];
        }
    } else {
        int t0 = (bi - 1024) * 256 + tid;
        const int stride = 32 * 256;
        for (int i = t0; i < 27 * 2 * 7 * 512; i += stride) {
            int j = i & 7, l = (i >> 3) & 63, rest = i >> 9;
            int m = rest % 7, ch = (rest / 7) & 1, tap = rest / 14;
            int co = m * 16 + (l & 15);
            int ci = ch * 32 + (l >> 4) * 8 + j;
            pA1[i] = (co < COFF) ? f2bf(w_off[(co * 67 + ci) * 27 + tap]) : (ushort)0;
        }
        for (int i = t0; i < 3 * 7 * 512; i += stride) {
            int j = i & 7, l = (i >> 3) & 63, rest = i >> 9;
            int m = rest % 7, t = rest / 7;
            int co = m * 16 + (l & 15);
            int flatk = t * 32 + (l >> 4) * 8 + j;
            ushort v = 0;
            if (co < COFF && flatk < 81) {
                int cc = flatk / 27, tap = flatk % 27;
                v = f2bf(w_off[(co * 67 + 64 + cc) * 27 + tap]);
            }
            pAc[i] = v;
        }
        for (int i = t0; i < 27 * 2 * 4 * 512; i += stride) {
            int j = i & 7, l = (i >> 3) & 63;
            int m = (i >> 9) & 3, ch = (i >> 11) & 1, k = i >> 12;
            int o = m * 16 + (l & 15);
            int c = ch * 32 + (l >> 4) * 8 + j;
            pW[i] = f2bf(w_dcn[(o * 64 + c) * 27 + k]);
        }
    }
}

// ---------------- kernel B: fused conv -> corners -> sample+GEMM ------------
// block: 16 sp; stage-2: 2 k-streams x 2 p-halves, full-line gathers,
// LDS bounce into MFMA B-frag layout (XOR-swizzled, double-buffered)
__global__ __launch_bounds__(256, 4) void k_fused(
    const ushort* __restrict__ xt, const ushort* __restrict__ pA1,
    const ushort* __restrict__ pAc, const ushort* __restrict__ pW,
    const float* __restrict__ b_off, const float* __restrict__ b_dcn,
    float* __restrict__ out)
{
    __shared__ __align__(16) char smem[33152];
    ushort* pred_lds = (ushort*)smem;            // 3456 B  bf16 [108][16]
    char*   region   = smem + 3456;              // 21504 B union:
    //   red1: f32x4[(w1*7+m)*64+lane]           (21504 B)
    //   cwi : uint4[(k*2+half)*16+p]            (13824 B)  pre-shifted byte idx
    //   cww : uint4[k*16+p] at +13824           ( 6912 B)  8 packed bf16 wgts
    //   red2: f32x4[(wv*4+m)*64+lane]           (16384 B)
    char*   Sbuf     = smem + 24960;             // 8192 B: [str][buf][16p][128B]

    const int bi   = blockIdx.x;
    const int b    = bi >> 9;
    const int sp16 = bi & 511;
    const int spg  = sp16 * 16;
    const int d    = sp16 >> 6;
    const int h    = (sp16 >> 1) & 31;
    const int w0   = (sp16 & 1) * 16;
    const int tid = threadIdx.x;
    const int wv = tid >> 6, lane = tid & 63, q = lane >> 4, r16 = lane & 15;
    const ushort* __restrict__ xb = xt + (size_t)b * DHW * 64;

    // ===== stage 1: offset conv, 57 K-chunks interleaved over 4 waves =====
    f32x4 acc1[7] = {};
    for (int c = wv; c < 57; c += 4) {
        bf16x8 bf = {};
        const ushort* pa;
        if (c < 54) {
            int tap = c >> 1, ch = c & 1;
            int dz = tap / 9, rem9 = tap - dz * 9, dy = rem9 / 3, dx = rem9 - dy * 3;
            int zz = d + dz - 1, yy = h + dy - 1, xx = w0 + r16 + dx - 1;
            bool ok = ((unsigned)zz < 8u) & ((unsigned)yy < 32u) & ((unsigned)xx < 32u);
            if (ok)
                bf = *(const bf16x8*)(xb + (size_t)((zz << 10) + (yy << 5) + xx) * 64
                                      + ch * 32 + q * 8);
            pa = pA1 + (size_t)((tap * 2 + ch) * 7) * 512 + lane * 8;
        } else {
            int t = c - 54;
            #pragma unroll
            for (int j = 0; j < 8; ++j) {
                int flatk = t * 32 + q * 8 + j;
                int cc = flatk / 27, tap = flatk % 27;
                int dz = tap / 9, rem9 = tap - dz * 9, dy = rem9 / 3, dx = rem9 - dy * 3;
                int zz = d + dz - 1, yy = h + dy - 1, xx = w0 + r16 + dx - 1;
                bool ok = (flatk < 81) & ((unsigned)zz < 8u) & ((unsigned)yy < 32u)
                          & ((unsigned)xx < 32u);
                float val = 0.f;
                if (ok)
                    val = (cc == 0) ? (-1.f + (2.f / 7.f) * (float)zz)
                        : (cc == 1) ? (-1.f + (2.f / 31.f) * (float)yy)
                                    : (-1.f + (2.f / 31.f) * (float)xx);
                bf[j] = (short)f2bf(val);
            }
            pa = pAc + (size_t)(t * 7) * 512 + lane * 8;
        }
        #pragma unroll
        for (int m = 0; m < 7; ++m)
            acc1[m] = __builtin_amdgcn_mfma_f32_16x16x32_bf16(
                *(const bf16x8*)(pa + m * 512), bf, acc1[m], 0, 0, 0);
    }
    if (wv) {
        f32x4* red1 = (f32x4*)region;
        #pragma unroll
        for (int m = 0; m < 7; ++m)
            red1[((wv - 1) * 7 + m) * 64 + lane] = acc1[m];
    }
    __syncthreads();
    if (wv == 0) {
        const f32x4* red1 = (const f32x4*)region;
        #pragma unroll
        for (int m = 0; m < 7; ++m) {
            f32x4 s = acc1[m];
            #pragma unroll
            for (int w1 = 0; w1 < 3; ++w1)
                s += red1[(w1 * 7 + m) * 64 + lane];
            #pragma unroll
            for (int r = 0; r < 4; ++r) {
                int co = m * 16 + q * 4 + r;
                if (co < COFF)
                    pred_lds[co * 16 + r16] = f2bf(s[r] + b_off[co]);
            }
        }
    }
    __syncthreads();

    // ===== corner tables =====
    uint4* cwi = (uint4*)region;
    uint4* cww = (uint4*)(region + 13824);
    for (int kp = tid; kp < 27 * 16; kp += 256) {
        int k = kp >> 4, p = kp & 15;
        float offz = bf2f(pred_lds[(k * 3 + 0) * 16 + p]);
        float offy = bf2f(pred_lds[(k * 3 + 1) * 16 + p]);
        float offx = bf2f(pred_lds[(k * 3 + 2) * 16 + p]);
        float av   = bf2f(pred_lds[(81 + k) * 16 + p]);
        float alpha = 1.f / (1.f + __expf(-av));
        int kz = k / 9, rem = k - kz * 9, ky = rem / 3, kx = rem - ky * 3;
        float pz = (float)(d + kz - 1) + offz;
        float py = (float)(h + ky - 1) + offy;
        float px = (float)(w0 + p + kx - 1) + offx;
        float fz = floorf(pz), fy = floorf(py), fx = floorf(px);
        float tz = pz - fz, ty = py - fy, tx = px - fx;
        int iz0 = (int)fz, iy0 = (int)fy, ix0 = (int)fx;
        unsigned idxs[8]; float wgts[8];
        #pragma unroll
        for (int c8 = 0; c8 < 8; ++c8) {
            int czi = c8 >> 2, cyi = (c8 >> 1) & 1, cxi = c8 & 1;
            int iz = iz0 + czi, iy = iy0 + cyi, ix = ix0 + cxi;
            float wz = czi ? tz : 1.f - tz;
            float wy = cyi ? ty : 1.f - ty;
            float wx = cxi ? tx : 1.f - tx;
            bool ok = ((unsigned)iz < 8u) && ((unsigned)iy < 32u) && ((unsigned)ix < 32u);
            idxs[c8] = ok ? ((unsigned)((iz << 10) + (iy << 5) + ix) << 7) : 0u;
            wgts[c8] = ok ? wz * wy * wx * alpha : 0.f;
        }
        cwi[(k * 2 + 0) * 16 + p] = make_uint4(idxs[0], idxs[1], idxs[2], idxs[3]);
        cwi[(k * 2 + 1) * 16 + p] = make_uint4(idxs[4], idxs[5], idxs[6], idxs[7]);
        cww[k * 16 + p] = make_uint4(
            (unsigned)f2bf(wgts[0]) | ((unsigned)f2bf(wgts[1]) << 16),
            (unsigned)f2bf(wgts[2]) | ((unsigned)f2bf(wgts[3]) << 16),
            (unsigned)f2bf(wgts[4]) | ((unsigned)f2bf(wgts[5]) << 16),
            (unsigned)f2bf(wgts[6]) | ((unsigned)f2bf(wgts[7]) << 16));
    }
    __syncthreads();

    // ===== stage 2: full-line sample + LDS bounce + GEMM =====
    // waves: str = wv>>1 (k-stream: even/odd k), ph = wv&1 (p-half & ch-half)
    // lanes: pr = lane>>3 (position in half), cg = lane&7 (8-ch group)
    const int str = wv >> 1, ph = wv & 1;
    const int pr = lane >> 3, cg = lane & 7;
    const int p2 = ph * 8 + pr;
    const char* xbB = (const char*)xb + cg * 16;
    char* Sbase = Sbuf + str * 4096;
    const unsigned swz_w = (unsigned)(p2 * 128 + ((cg * 16) ^ ((p2 & 7) << 4)));
    const unsigned swz_r = (unsigned)(r16 * 128 + ((ph * 64 + q * 16) ^ ((r16 & 7) << 4)));

    f32x4 acc2[4] = {};
    for (int t = 0; t < 14; ++t) {
        const int k = 2 * t + str;
        char* Sb = Sbase + (t & 1) * 2048;
        if (k < 27) {
            uint4 wq = cww[k * 16 + p2];
            uint4 i0 = cwi[(k * 2 + 0) * 16 + p2];
            uint4 i1 = cwi[(k * 2 + 1) * 16 + p2];
            unsigned iv[8] = {i0.x, i0.y, i0.z, i0.w, i1.x, i1.y, i1.z, i1.w};
            unsigned wp[4] = {wq.x, wq.y, wq.z, wq.w};
            float sa[8] = {};
            #pragma unroll
            for (int cp = 0; cp < 4; ++cp) {
                uint4 xa = *(const uint4*)(xbB + iv[cp * 2 + 0]);
                uint4 xc = *(const uint4*)(xbB + iv[cp * 2 + 1]);
                unsigned ua[4] = {xa.x, xa.y, xa.z, xa.w};
                unsigned ub[4] = {xc.x, xc.y, xc.z, xc.w};
                #pragma unroll
                for (int dw = 0; dw < 4; ++dw) {
                    unsigned plo = __builtin_amdgcn_perm(ub[dw], ua[dw], 0x05040100u);
                    unsigned phi = __builtin_amdgcn_perm(ub[dw], ua[dw], 0x07060302u);
                    sa[dw * 2 + 0] = dot2bf(plo, wp[cp], sa[dw * 2 + 0]);
                    sa[dw * 2 + 1] = dot2bf(phi, wp[cp], sa[dw * 2 + 1]);
                }
            }
            uint4 pk;
            pk.x = (unsigned)f2bf(sa[0]) | ((unsigned)f2bf(sa[1]) << 16);
            pk.y = (unsigned)f2bf(sa[2]) | ((unsigned)f2bf(sa[3]) << 16);
            pk.z = (unsigned)f2bf(sa[4]) | ((unsigned)f2bf(sa[5]) << 16);
            pk.w = (unsigned)f2bf(sa[6]) | ((unsigned)f2bf(sa[7]) << 16);
            *(uint4*)(Sb + swz_w) = pk;
        }
        __syncthreads();
        if (k < 27) {
            bf16x8 bfv = *(const bf16x8*)(Sb + swz_r);
            const ushort* pwk = pW + (size_t)((k * 2 + ph) * 4) * 512 + lane * 8;
            #pragma unroll
            for (int m = 0; m < 4; ++m)
                acc2[m] = __builtin_amdgcn_mfma_f32_16x16x32_bf16(
                    *(const bf16x8*)(pwk + m * 512), bfv, acc2[m], 0, 0, 0);
        }
    }

    __syncthreads();
    f32x4* red2 = (f32x4*)region;
    #pragma unroll
    for (int m = 0; m < 4; ++m)
        red2[(wv * 4 + m) * 64 + lane] = acc2[m];
    __syncthreads();
    float* __restrict__ outb = out + (size_t)b * 64 * DHW + spg;
    f32x4 s = red2[(0 * 4 + wv) * 64 + lane];
    #pragma unroll
    for (int w1 = 1; w1 < 4; ++w1)
        s += red2[(w1 * 4 + wv) * 64 + lane];
    #pragma unroll
    for (int r = 0; r < 4; ++r) {
        int o = wv * 16 + q * 4 + r;
        outb[(size_t)o * DHW + r16] = s[r] + b_dcn[o];
    }
}

extern "C" void kernel_launch(void* const* d_in, const int* in_sizes, int n_in,
                              void* d_out, int out_size, void* d_ws, size_t ws_size,
                              hipStream_t stream) {
    const float* x     = (const float*)d_in[0];
    const float* w_off = (const float*)d_in[1];
    const float* b_off = (const float*)d_in[2];
    const float* w_dcn = (const float*)d_in[3];
    const float* b_dcn = (const float*)d_in[4];
    float* out = (float*)d_out;

    ushort* xt  = (ushort*)d_ws;                          // 2,097,152 B
    ushort* pA1 = (ushort*)((char*)d_ws + 2097152);       //   387,072 B
    ushort* pAc = (ushort*)((char*)d_ws + 2484224);       //    21,504 B
    ushort* pW  = (ushort*)((char*)d_ws + 2505728);       //   221,184 B

    k_prep <<<1056, 256, 0, stream>>>(x, w_off, w_dcn, xt, pA1, pAc, pW);
    k_fused<<<1024, 256, 0, stream>>>(xt, pA1, pAc, pW, b_off, b_dcn, out);
}